// Round 1
// baseline (923.430 us; speedup 1.0000x reference)
//
#include <hip/hip_runtime.h>

#define NN 50000
#define ALPHA 0.2f

__device__ __forceinline__ float elu_f(float x) {
  return x > 0.f ? x : __expf(x) - 1.f;
}

// ---------------- CSR build ----------------
__global__ void hist_kernel(const int* __restrict__ src, int* __restrict__ cnt, int E) {
  int e = blockIdx.x * blockDim.x + threadIdx.x;
  if (e < E) atomicAdd(&cnt[src[e]], 1);
}

__global__ __launch_bounds__(1024) void scan_kernel(const int* __restrict__ cnt,
                                                    int* __restrict__ row_ptr,
                                                    int* __restrict__ nxt, int n) {
  __shared__ int sh[1024];
  int carry = 0;
  if (threadIdx.x == 0) row_ptr[0] = 0;
  for (int base = 0; base < n; base += 1024) {
    int i = base + threadIdx.x;
    int v = (i < n) ? cnt[i] : 0;
    sh[threadIdx.x] = v;
    __syncthreads();
    for (int off = 1; off < 1024; off <<= 1) {
      int t = (threadIdx.x >= off) ? sh[threadIdx.x - off] : 0;
      __syncthreads();
      sh[threadIdx.x] += t;
      __syncthreads();
    }
    if (i < n) {
      int incl = carry + sh[threadIdx.x];
      row_ptr[i + 1] = incl;
      nxt[i] = incl - v;            // exclusive prefix = segment start
    }
    carry += sh[1023];
    __syncthreads();
  }
}

__global__ void scatter_kernel(const int* __restrict__ src, const int* __restrict__ dst,
                               int* __restrict__ nxt, int* __restrict__ col, int E) {
  int e = blockIdx.x * blockDim.x + threadIdx.x;
  if (e < E) {
    int p = atomicAdd(&nxt[src[e]], 1);
    col[p] = dst[e];
  }
}

// ---------------- fp32 tiled GEMM: C[r, y*64+c] = X[r,:K] . B_all[y][:,c] ----------------
// B_all = stack of per-column-block [K,64] row-major matrices (W is [H][256][64]).
__global__ __launch_bounds__(256) void gemm_kernel(const float* __restrict__ X,
                                                   const float* __restrict__ B_all,
                                                   float* __restrict__ C,
                                                   int N, int K, int ldc) {
  __shared__ float As[16][136];   // [k][row], 128 rows + pad
  __shared__ float Bs[16][68];    // [k][col], 64 cols + pad
  const float* B = B_all + (size_t)blockIdx.y * K * 64;
  int r0 = blockIdx.x * 128;
  int tx = threadIdx.x & 15;      // col quad
  int ty = threadIdx.x >> 4;      // row octet
  float acc[8][4];
#pragma unroll
  for (int i = 0; i < 8; ++i)
#pragma unroll
    for (int j = 0; j < 4; ++j) acc[i][j] = 0.f;

  for (int k0 = 0; k0 < K; k0 += 16) {
#pragma unroll
    for (int it = 0; it < 2; ++it) {        // stage A: 128 rows x 16 k (float4)
      int l = threadIdx.x + it * 256;       // 0..511
      int row = l >> 2;
      int kq = (l & 3) << 2;
      int r = r0 + row;
      float4 v = make_float4(0.f, 0.f, 0.f, 0.f);
      if (r < N) v = *(const float4*)(X + (size_t)r * K + k0 + kq);
      As[kq][row] = v.x; As[kq + 1][row] = v.y; As[kq + 2][row] = v.z; As[kq + 3][row] = v.w;
    }
    {                                       // stage B: 16 k x 64 cols (float4)
      int kk = threadIdx.x >> 4;
      int c = (threadIdx.x & 15) << 2;
      *(float4*)&Bs[kk][c] = *(const float4*)(B + (size_t)(k0 + kk) * 64 + c);
    }
    __syncthreads();
#pragma unroll
    for (int kk = 0; kk < 16; ++kk) {
      float4 b4 = *(const float4*)&Bs[kk][tx << 2];
      float4 a0 = *(const float4*)&As[kk][ty << 3];
      float4 a1 = *(const float4*)&As[kk][(ty << 3) + 4];
      float av[8] = {a0.x, a0.y, a0.z, a0.w, a1.x, a1.y, a1.z, a1.w};
      float bv[4] = {b4.x, b4.y, b4.z, b4.w};
#pragma unroll
      for (int i = 0; i < 8; ++i)
#pragma unroll
        for (int j = 0; j < 4; ++j) acc[i][j] += av[i] * bv[j];
    }
    __syncthreads();
  }
#pragma unroll
  for (int i = 0; i < 8; ++i) {
    int r = r0 + (ty << 3) + i;
    if (r < N) {
      float4 v = make_float4(acc[i][0], acc[i][1], acc[i][2], acc[i][3]);
      *(float4*)(C + (size_t)r * ldc + blockIdx.y * 64 + (tx << 2)) = v;
    }
  }
}

// ---------------- attention score dots ----------------
// ss[n,h] = h1[n, h*64:] . a[h,:64] ; sd[n,h] = h1[n, h*64:] . a[h,64:]
__global__ __launch_bounds__(256) void sdots1_kernel(const float* __restrict__ h1,
    const float* __restrict__ a, float* __restrict__ ss, float* __restrict__ sd, int N) {
  int wid = threadIdx.x >> 6, lane = threadIdx.x & 63;
  int n = blockIdx.x * 4 + wid;
  if (n >= N) return;
#pragma unroll
  for (int h = 0; h < 8; ++h) {
    float v = h1[(size_t)n * 512 + h * 64 + lane];
    float p = v * a[h * 128 + lane];
    float q = v * a[h * 128 + 64 + lane];
#pragma unroll
    for (int off = 32; off > 0; off >>= 1) {
      p += __shfl_down(p, off, 64);
      q += __shfl_down(q, off, 64);
    }
    if (lane == 0) { ss[n * 8 + h] = p; sd[n * 8 + h] = q; }
  }
}

__global__ __launch_bounds__(256) void sdots2_kernel(const float* __restrict__ h2,
    const float* __restrict__ ao, float* __restrict__ ss, float* __restrict__ sd, int N) {
  int wid = threadIdx.x >> 6, lane = threadIdx.x & 63;
  int n = blockIdx.x * 4 + wid;
  if (n >= N) return;
  float v = h2[(size_t)n * 64 + lane];
  float p = v * ao[lane];
  float q = v * ao[64 + lane];
#pragma unroll
  for (int off = 32; off > 0; off >>= 1) {
    p += __shfl_down(p, off, 64);
    q += __shfl_down(q, off, 64);
  }
  if (lane == 0) { ss[n] = p; sd[n] = q; }
}

// ---------------- layer-1 aggregation (8 heads fused), writes xc = elu(num/rowsum) ----------------
// one block (128 thr) per node; thread t owns float4 slice [4t,4t+4) of the 512-wide row; head = t>>4
__global__ __launch_bounds__(128) void agg1_kernel(const float* __restrict__ h1,
    const float* __restrict__ ss1, const float* __restrict__ sd1,
    const int* __restrict__ row_ptr, const int* __restrict__ col,
    float* __restrict__ xc, int N) {
  int n = blockIdx.x;
  int t = threadIdx.x;
  int h = t >> 4;
  float ssn = ss1[n * 8 + h];
  int k0 = row_ptr[n], k1 = row_ptr[n + 1];
  float ax = 0.f, ay = 0.f, az = 0.f, aw = 0.f, rs = 0.f;
  for (int k = k0; k < k1; ++k) {
    int d = col[k];
    float s = ssn + sd1[d * 8 + h];
    float e = __expf(-(s > 0.f ? s : ALPHA * s));
    float4 v = *(const float4*)(h1 + (size_t)d * 512 + (t << 2));
    ax += e * v.x; ay += e * v.y; az += e * v.z; aw += e * v.w;
    rs += e;
  }
  float inv = 1.f / rs;
  float4 o;
  o.x = elu_f(ax * inv); o.y = elu_f(ay * inv);
  o.z = elu_f(az * inv); o.w = elu_f(aw * inv);
  *(float4*)(xc + (size_t)n * 512 + (t << 2)) = o;
}

// ---------------- layer-2 aggregation, writes xo = elu(num/rowsum) ----------------
__global__ __launch_bounds__(256) void agg2_kernel(const float* __restrict__ h2,
    const float* __restrict__ ss2, const float* __restrict__ sd2,
    const int* __restrict__ row_ptr, const int* __restrict__ col,
    float* __restrict__ xo, int N) {
  int wid = threadIdx.x >> 6, lane = threadIdx.x & 63;
  int n = blockIdx.x * 4 + wid;
  if (n >= N) return;
  float ssn = ss2[n];
  int k0 = row_ptr[n], k1 = row_ptr[n + 1];
  float acc = 0.f, rs = 0.f;
  for (int k = k0; k < k1; ++k) {
    int d = col[k];
    float s = ssn + sd2[d];
    float e = __expf(-(s > 0.f ? s : ALPHA * s));
    acc += e * h2[(size_t)d * 64 + lane];
    rs += e;
  }
  float o = acc / rs;
  xo[(size_t)n * 64 + lane] = elu_f(o);
}

// ---------------- final classifier: out[n,c] = xo[n,:] . mlp_w[c,:] + mlp_b[c] ----------------
__global__ __launch_bounds__(256) void final_kernel(const float* __restrict__ xo,
    const float* __restrict__ mlp_w, const float* __restrict__ mlp_b,
    float* __restrict__ out, int total) {
  __shared__ float wsh[40 * 65];   // pad 65 -> distinct banks across c
  __shared__ float bsh[40];
  for (int i = threadIdx.x; i < 40 * 64; i += 256) wsh[(i >> 6) * 65 + (i & 63)] = mlp_w[i];
  if (threadIdx.x < 40) bsh[threadIdx.x] = mlp_b[threadIdx.x];
  __syncthreads();
  int idx = blockIdx.x * 256 + threadIdx.x;
  if (idx >= total) return;
  int n = idx / 40, c = idx - n * 40;
  const float* xr = xo + (size_t)n * 64;
  const float* wr = wsh + c * 65;
  float acc = bsh[c];
#pragma unroll
  for (int j = 0; j < 64; ++j) acc += xr[j] * wr[j];
  out[idx] = acc;
}

extern "C" void kernel_launch(void* const* d_in, const int* in_sizes, int n_in,
                              void* d_out, int out_size, void* d_ws, size_t ws_size,
                              hipStream_t stream) {
  (void)n_in; (void)out_size; (void)ws_size;
  const float* x  = (const float*)d_in[0];
  const int*   ei = (const int*)d_in[1];
  const float* W  = (const float*)d_in[2];
  const float* a  = (const float*)d_in[3];
  const float* Wo = (const float*)d_in[4];
  const float* ao = (const float*)d_in[5];
  const float* mw = (const float*)d_in[6];
  const float* mb = (const float*)d_in[7];
  float* out = (float*)d_out;

  const int N = NN;
  const int E = in_sizes[1] / 2;
  const int* src = ei;
  const int* dst = ei + E;

  char* ws = (char*)d_ws;
  size_t off = 0;
  auto alloc = [&](size_t bytes) {
    char* p = ws + off;
    off = (off + bytes + 255) & ~(size_t)255;
    return p;
  };
  float* h1      = (float*)alloc((size_t)N * 512 * 4);
  float* xc      = (float*)alloc((size_t)N * 512 * 4);
  float* ss1     = (float*)alloc((size_t)N * 8 * 4);
  float* sd1     = (float*)alloc((size_t)N * 8 * 4);
  int*   row_ptr = (int*)  alloc((size_t)(N + 1) * 4);
  int*   nxt     = (int*)  alloc((size_t)N * 4);
  int*   cnt     = (int*)  alloc((size_t)N * 4);
  int*   colv    = (int*)  alloc((size_t)E * 4);
  // layer-2 buffers overlay the h1 region (h1 is dead after agg1)
  float* h2  = h1;                       // N*64
  float* ss2 = h1 + (size_t)N * 64;      // N
  float* sd2 = ss2 + N;                  // N
  float* xo  = sd2 + N;                  // N*64

  int eb = (E + 255) / 256;

  hipMemsetAsync(cnt, 0, (size_t)N * 4, stream);
  hipLaunchKernelGGL(hist_kernel, dim3(eb), dim3(256), 0, stream, src, cnt, E);
  hipLaunchKernelGGL(scan_kernel, dim3(1), dim3(1024), 0, stream, cnt, row_ptr, nxt, N);
  hipLaunchKernelGGL(scatter_kernel, dim3(eb), dim3(256), 0, stream, src, dst, nxt, colv, E);

  // layer 1: h1 = x @ W (8 heads), scores, aggregate -> xc
  hipLaunchKernelGGL(gemm_kernel, dim3((N + 127) / 128, 8), dim3(256), 0, stream,
                     x, W, h1, N, 256, 512);
  hipLaunchKernelGGL(sdots1_kernel, dim3((N + 3) / 4), dim3(256), 0, stream, h1, a, ss1, sd1, N);
  hipLaunchKernelGGL(agg1_kernel, dim3(N), dim3(128), 0, stream,
                     h1, ss1, sd1, row_ptr, colv, xc, N);

  // layer 2: h2 = xc @ Wo, scores, aggregate -> xo
  hipLaunchKernelGGL(gemm_kernel, dim3((N + 127) / 128, 1), dim3(256), 0, stream,
                     xc, Wo, h2, N, 512, 64);
  hipLaunchKernelGGL(sdots2_kernel, dim3((N + 3) / 4), dim3(256), 0, stream, h2, ao, ss2, sd2, N);
  hipLaunchKernelGGL(agg2_kernel, dim3((N + 3) / 4), dim3(256), 0, stream,
                     h2, ss2, sd2, row_ptr, colv, xo, N);

  // classifier
  hipLaunchKernelGGL(final_kernel, dim3((N * 40 + 255) / 256), dim3(256), 0, stream,
                     xo, mw, mb, out, N * 40);
}

// Round 2
// 654.981 us; speedup vs baseline: 1.4099x; 1.4099x over previous
//
#include <hip/hip_runtime.h>

#define NN 50000
#define HH 8
#define ALPHA 0.2f

__device__ __forceinline__ float elu_f(float x) {
  return x > 0.f ? x : __expf(x) - 1.f;
}

__device__ __forceinline__ unsigned short f2bf(float f) {
  unsigned int u = __float_as_uint(f);
  unsigned int r = (u + 0x7fffu + ((u >> 16) & 1u)) >> 16;
  return (unsigned short)r;
}

// ---------------- CSR build ----------------
__global__ void hist_kernel(const int* __restrict__ src, int* __restrict__ cnt, int E) {
  int e = blockIdx.x * blockDim.x + threadIdx.x;
  if (e < E) atomicAdd(&cnt[src[e]], 1);
}

__global__ __launch_bounds__(1024) void scan_blocks_kernel(const int* __restrict__ cnt,
    int* __restrict__ tmp, int* __restrict__ bsum, int n) {
  __shared__ int sh[1024];
  int i = blockIdx.x * 1024 + threadIdx.x;
  int v = (i < n) ? cnt[i] : 0;
  sh[threadIdx.x] = v;
  __syncthreads();
  for (int off = 1; off < 1024; off <<= 1) {
    int t = (threadIdx.x >= off) ? sh[threadIdx.x - off] : 0;
    __syncthreads();
    sh[threadIdx.x] += t;
    __syncthreads();
  }
  if (i < n) tmp[i] = sh[threadIdx.x] - v;          // exclusive within block
  if (threadIdx.x == 1023) bsum[blockIdx.x] = sh[1023];
}

__global__ __launch_bounds__(64) void scan_top_kernel(const int* __restrict__ bsum,
    int* __restrict__ boffs, int nb) {
  int L = threadIdx.x;
  int v = (L < nb) ? bsum[L] : 0;
  int incl = v;
#pragma unroll
  for (int off = 1; off < 64; off <<= 1) {
    int t = __shfl_up(incl, off, 64);
    if (L >= off) incl += t;
  }
  if (L < nb) boffs[L] = incl - v;                  // exclusive block offsets
}

__global__ __launch_bounds__(1024) void scan_apply_kernel(const int* __restrict__ tmp,
    const int* __restrict__ boffs, int* __restrict__ row_ptr, int* __restrict__ nxt,
    int n, int E) {
  int i = blockIdx.x * 1024 + threadIdx.x;
  if (i < n) {
    int s = tmp[i] + boffs[blockIdx.x];
    row_ptr[i] = s;
    nxt[i] = s;
  }
  if (i == 0) row_ptr[n] = E;
}

__global__ void scatter_kernel(const int* __restrict__ src, const int* __restrict__ dst,
                               int* __restrict__ nxt, int* __restrict__ col, int E) {
  int e = blockIdx.x * blockDim.x + threadIdx.x;
  if (e < E) {
    int p = atomicAdd(&nxt[src[e]], 1);
    col[p] = dst[e];
  }
}

// ---------------- fused GEMM + attention-score epilogue ----------------
// C[y][r][c] = X[r,:K] . B_all[y][:,c]   (c in [0,64))
// ss[y*N+r] = C[y][r][:] . Aatt[y][:64] ; sd[y*N+r] = C[y][r][:] . Aatt[y][64:]
// BF16OUT: table written as bf16 [H][N][64]; else fp32 [N][64] (grid.y==1).
template <bool BF16OUT>
__global__ __launch_bounds__(256) void gemm_fused_kernel(const float* __restrict__ X,
    const float* __restrict__ B_all, const float* __restrict__ Aatt,
    void* __restrict__ Cout, float* __restrict__ ss, float* __restrict__ sd,
    int N, int K) {
  __shared__ float As[16][136];   // [k][row], 128 rows + pad
  __shared__ float Bs[16][68];    // [k][col], 64 cols + pad
  const int y = blockIdx.y;
  const float* B = B_all + (size_t)y * K * 64;
  int r0 = blockIdx.x * 128;
  int tx = threadIdx.x & 15;      // col quad
  int ty = threadIdx.x >> 4;     // row octet
  float acc[8][4];
#pragma unroll
  for (int i = 0; i < 8; ++i)
#pragma unroll
    for (int j = 0; j < 4; ++j) acc[i][j] = 0.f;

  for (int k0 = 0; k0 < K; k0 += 16) {
#pragma unroll
    for (int it = 0; it < 2; ++it) {        // stage A: 128 rows x 16 k
      int l = threadIdx.x + it * 256;       // 0..511
      int row = l >> 2;
      int kq = (l & 3) << 2;
      int r = r0 + row;
      float4 v = make_float4(0.f, 0.f, 0.f, 0.f);
      if (r < N) v = *(const float4*)(X + (size_t)r * K + k0 + kq);
      As[kq][row] = v.x; As[kq + 1][row] = v.y; As[kq + 2][row] = v.z; As[kq + 3][row] = v.w;
    }
    {                                       // stage B: 16 k x 64 cols
      int kk = threadIdx.x >> 4;
      int c = (threadIdx.x & 15) << 2;
      *(float4*)&Bs[kk][c] = *(const float4*)(B + (size_t)(k0 + kk) * 64 + c);
    }
    __syncthreads();
#pragma unroll
    for (int kk = 0; kk < 16; ++kk) {
      float4 b4 = *(const float4*)&Bs[kk][tx << 2];
      float4 a0 = *(const float4*)&As[kk][ty << 3];
      float4 a1 = *(const float4*)&As[kk][(ty << 3) + 4];
      float av[8] = {a0.x, a0.y, a0.z, a0.w, a1.x, a1.y, a1.z, a1.w};
      float bv[4] = {b4.x, b4.y, b4.z, b4.w};
#pragma unroll
      for (int i = 0; i < 8; ++i)
#pragma unroll
        for (int j = 0; j < 4; ++j) acc[i][j] += av[i] * bv[j];
    }
    __syncthreads();
  }

  // epilogue: scores + table write
  float4 as4 = *(const float4*)(Aatt + y * 128 + (tx << 2));
  float4 ad4 = *(const float4*)(Aatt + y * 128 + 64 + (tx << 2));
  size_t yN = (size_t)y * N;
#pragma unroll
  for (int i = 0; i < 8; ++i) {
    int r = r0 + (ty << 3) + i;
    float ps = acc[i][0] * as4.x + acc[i][1] * as4.y + acc[i][2] * as4.z + acc[i][3] * as4.w;
    float pd = acc[i][0] * ad4.x + acc[i][1] * ad4.y + acc[i][2] * ad4.z + acc[i][3] * ad4.w;
#pragma unroll
    for (int off = 1; off < 16; off <<= 1) {
      ps += __shfl_xor(ps, off, 64);
      pd += __shfl_xor(pd, off, 64);
    }
    if (r < N) {
      if (tx == 0) { ss[yN + r] = ps; sd[yN + r] = pd; }
      if (BF16OUT) {
        ushort4 pk;
        pk.x = f2bf(acc[i][0]); pk.y = f2bf(acc[i][1]);
        pk.z = f2bf(acc[i][2]); pk.w = f2bf(acc[i][3]);
        *(ushort4*)((unsigned short*)Cout + (yN + r) * 64 + (tx << 2)) = pk;
      } else {
        *(float4*)((float*)Cout + (size_t)r * 64 + (tx << 2)) =
            make_float4(acc[i][0], acc[i][1], acc[i][2], acc[i][3]);
      }
    }
  }
}

// ---------------- layer-1 aggregation: head-major bf16 table ----------------
// grid (ceil(N/4), H), 256 thr = 4 waves, one wave per node.
// per chunk of <=64 edges: lane j computes e_j; then 8 edges per uint4 load round.
__global__ __launch_bounds__(256) void agg1_kernel(const unsigned short* __restrict__ h1b,
    const float* __restrict__ ss1, const float* __restrict__ sd1,
    const int* __restrict__ row_ptr, const int* __restrict__ col,
    float* __restrict__ xc, int N) {
  int h = blockIdx.y;
  int wid = threadIdx.x >> 6, L = threadIdx.x & 63;
  int n = blockIdx.x * 4 + wid;
  if (n >= N) return;
  const size_t hN = (size_t)h * N;
  float ssn = ss1[hN + n];
  int k0 = row_ptr[n];
  int deg = row_ptr[n + 1] - k0;
  const unsigned short* table = h1b + hN * 64;
  float acc[8];
#pragma unroll
  for (int t = 0; t < 8; ++t) acc[t] = 0.f;
  float rs = 0.f;

  for (int c0 = 0; c0 < deg; c0 += 64) {
    int j = c0 + L;
    int d = 0;
    float e = 0.f;
    if (j < deg) {
      d = col[k0 + j];
      float s = ssn + sd1[hN + d];
      e = __expf(-(s > 0.f ? s : ALPHA * s));
    }
    rs += e;
    int m = min(64, deg - c0);
    for (int g = 0; g < m; g += 8) {
      int sl = g + (L >> 3);
      float eg = __shfl(e, sl, 64);
      int dg = __shfl(d, sl, 64);
      uint4 rv = *(const uint4*)(table + (size_t)dg * 64 + ((L & 7) << 3));
      float vals[8];
      const unsigned int* up = (const unsigned int*)&rv;
#pragma unroll
      for (int w = 0; w < 4; ++w) {
        vals[2 * w]     = __uint_as_float(up[w] << 16);
        vals[2 * w + 1] = __uint_as_float(up[w] & 0xffff0000u);
      }
#pragma unroll
      for (int t = 0; t < 8; ++t) acc[t] += eg * vals[t];
    }
  }
#pragma unroll
  for (int off = 8; off < 64; off <<= 1)
#pragma unroll
    for (int t = 0; t < 8; ++t) acc[t] += __shfl_xor(acc[t], off, 64);
#pragma unroll
  for (int off = 1; off < 64; off <<= 1) rs += __shfl_xor(rs, off, 64);

  if (L < 8) {
    float inv = 1.f / rs;
    float o[8];
#pragma unroll
    for (int t = 0; t < 8; ++t) o[t] = elu_f(acc[t] * inv);
    float4* p = (float4*)(xc + (size_t)n * 512 + h * 64 + L * 8);
    p[0] = make_float4(o[0], o[1], o[2], o[3]);
    p[1] = make_float4(o[4], o[5], o[6], o[7]);
  }
}

// ---------------- layer-2 aggregation: fp32 table [N][64] ----------------
__global__ __launch_bounds__(256) void agg2_kernel(const float* __restrict__ h2,
    const float* __restrict__ ss2, const float* __restrict__ sd2,
    const int* __restrict__ row_ptr, const int* __restrict__ col,
    float* __restrict__ xo, int N) {
  int wid = threadIdx.x >> 6, L = threadIdx.x & 63;
  int n = blockIdx.x * 4 + wid;
  if (n >= N) return;
  float ssn = ss2[n];
  int k0 = row_ptr[n];
  int deg = row_ptr[n + 1] - k0;
  float ax = 0.f, ay = 0.f, az = 0.f, aw = 0.f, rs = 0.f;

  for (int c0 = 0; c0 < deg; c0 += 64) {
    int j = c0 + L;
    int d = 0;
    float e = 0.f;
    if (j < deg) {
      d = col[k0 + j];
      float s = ssn + sd2[d];
      e = __expf(-(s > 0.f ? s : ALPHA * s));
    }
    rs += e;
    int m = min(64, deg - c0);
    for (int g = 0; g < m; g += 4) {
      int sl = g + (L >> 4);
      float eg = __shfl(e, sl, 64);
      int dg = __shfl(d, sl, 64);
      float4 v = *(const float4*)(h2 + (size_t)dg * 64 + ((L & 15) << 2));
      ax += eg * v.x; ay += eg * v.y; az += eg * v.z; aw += eg * v.w;
    }
  }
#pragma unroll
  for (int off = 16; off < 64; off <<= 1) {
    ax += __shfl_xor(ax, off, 64);
    ay += __shfl_xor(ay, off, 64);
    az += __shfl_xor(az, off, 64);
    aw += __shfl_xor(aw, off, 64);
  }
#pragma unroll
  for (int off = 1; off < 64; off <<= 1) rs += __shfl_xor(rs, off, 64);

  if (L < 16) {
    float inv = 1.f / rs;
    float4 o;
    o.x = elu_f(ax * inv); o.y = elu_f(ay * inv);
    o.z = elu_f(az * inv); o.w = elu_f(aw * inv);
    *(float4*)(xo + (size_t)n * 64 + (L << 2)) = o;
  }
}

// ---------------- final classifier ----------------
__global__ __launch_bounds__(256) void final_kernel(const float* __restrict__ xo,
    const float* __restrict__ mlp_w, const float* __restrict__ mlp_b,
    float* __restrict__ out, int total) {
  __shared__ float wsh[40 * 65];
  __shared__ float bsh[40];
  for (int i = threadIdx.x; i < 40 * 64; i += 256) wsh[(i >> 6) * 65 + (i & 63)] = mlp_w[i];
  if (threadIdx.x < 40) bsh[threadIdx.x] = mlp_b[threadIdx.x];
  __syncthreads();
  int idx = blockIdx.x * 256 + threadIdx.x;
  if (idx >= total) return;
  int n = idx / 40, c = idx - n * 40;
  const float* xr = xo + (size_t)n * 64;
  const float* wr = wsh + c * 65;
  float acc = bsh[c];
#pragma unroll
  for (int j = 0; j < 64; ++j) acc += xr[j] * wr[j];
  out[idx] = acc;
}

extern "C" void kernel_launch(void* const* d_in, const int* in_sizes, int n_in,
                              void* d_out, int out_size, void* d_ws, size_t ws_size,
                              hipStream_t stream) {
  (void)n_in; (void)out_size; (void)ws_size;
  const float* x  = (const float*)d_in[0];
  const int*   ei = (const int*)d_in[1];
  const float* W  = (const float*)d_in[2];
  const float* a  = (const float*)d_in[3];
  const float* Wo = (const float*)d_in[4];
  const float* ao = (const float*)d_in[5];
  const float* mw = (const float*)d_in[6];
  const float* mb = (const float*)d_in[7];
  float* out = (float*)d_out;

  const int N = NN;
  const int E = in_sizes[1] / 2;
  const int* src = ei;
  const int* dst = ei + E;

  char* ws = (char*)d_ws;
  size_t off = 0;
  auto alloc = [&](size_t bytes) {
    char* p = ws + off;
    off = (off + bytes + 255) & ~(size_t)255;
    return p;
  };
  unsigned short* h1b = (unsigned short*)alloc((size_t)HH * N * 64 * 2); // 51.2 MB
  float* ss1     = (float*)alloc((size_t)HH * N * 4);
  float* sd1     = (float*)alloc((size_t)HH * N * 4);
  float* xc      = (float*)alloc((size_t)N * 512 * 4);                   // 102.4 MB
  float* h2      = (float*)alloc((size_t)N * 64 * 4);
  float* ss2     = (float*)alloc((size_t)N * 4);
  float* sd2     = (float*)alloc((size_t)N * 4);
  float* xo      = (float*)alloc((size_t)N * 64 * 4);
  int*   row_ptr = (int*)  alloc((size_t)(N + 1) * 4);
  int*   nxt     = (int*)  alloc((size_t)N * 4);
  int*   cnt     = (int*)  alloc((size_t)N * 4);
  int*   tmp     = (int*)  alloc((size_t)N * 4);
  int*   bsum    = (int*)  alloc(64 * 4);
  int*   boffs   = (int*)  alloc(64 * 4);
  int*   colv    = (int*)  alloc((size_t)E * 4);

  int eb = (E + 255) / 256;
  int nb1024 = (N + 1023) / 1024;   // 49

  hipMemsetAsync(cnt, 0, (size_t)N * 4, stream);
  hipLaunchKernelGGL(hist_kernel, dim3(eb), dim3(256), 0, stream, src, cnt, E);
  hipLaunchKernelGGL(scan_blocks_kernel, dim3(nb1024), dim3(1024), 0, stream, cnt, tmp, bsum, N);
  hipLaunchKernelGGL(scan_top_kernel, dim3(1), dim3(64), 0, stream, bsum, boffs, nb1024);
  hipLaunchKernelGGL(scan_apply_kernel, dim3(nb1024), dim3(1024), 0, stream, tmp, boffs, row_ptr, nxt, N, E);
  hipLaunchKernelGGL(scatter_kernel, dim3(eb), dim3(256), 0, stream, src, dst, nxt, colv, E);

  // layer 1: h1b(bf16, head-major) + scores, then aggregate -> xc
  hipLaunchKernelGGL((gemm_fused_kernel<true>), dim3((N + 127) / 128, HH), dim3(256), 0, stream,
                     x, W, a, (void*)h1b, ss1, sd1, N, 256);
  hipLaunchKernelGGL(agg1_kernel, dim3((N + 3) / 4, HH), dim3(256), 0, stream,
                     h1b, ss1, sd1, row_ptr, colv, xc, N);

  // layer 2: h2 = xc @ Wo + scores, aggregate -> xo
  hipLaunchKernelGGL((gemm_fused_kernel<false>), dim3((N + 127) / 128, 1), dim3(256), 0, stream,
                     xc, Wo, ao, (void*)h2, ss2, sd2, N, 512);
  hipLaunchKernelGGL(agg2_kernel, dim3((N + 3) / 4), dim3(256), 0, stream,
                     h2, ss2, sd2, row_ptr, colv, xo, N);

  // classifier
  hipLaunchKernelGGL(final_kernel, dim3((N * 40 + 255) / 256), dim3(256), 0, stream,
                     xo, mw, mb, out, N * 40);
}